// Round 1
// baseline (217.585 us; speedup 1.0000x reference)
//
#include <hip/hip_runtime.h>
#include <hip/hip_bf16.h>
#include <stdint.h>

// B=8, N=1024, D=1024.  out = relu(adj @ (y@W) / adj_sumrow + b + x)
// R4: occupancy fix. GEMM tiles 128x64, BK=32 -> LDS 24KB/block -> 4 blocks/CU
// (was 64KB -> 2/CU), grid 1024 = exactly 4x256 CUs, one dispatch round.
// Counted-vmcnt double-buffered pipeline kept identical in structure (vmcnt(3)).

typedef float  f32x4  __attribute__((ext_vector_type(4)));
typedef __bf16 bf16x8 __attribute__((ext_vector_type(8)));

__device__ __forceinline__ unsigned short f2bf(float f) {
  union { float f; unsigned int u; } c; c.f = f;
  unsigned int u = c.u;
  u += 0x7FFFu + ((u >> 16) & 1u);   // RNE; inputs finite
  return (unsigned short)(u >> 16);
}

__device__ __forceinline__ void async_cp16(const void* g, void* l) {
  __builtin_amdgcn_global_load_lds(
      (const __attribute__((address_space(1))) unsigned int*)g,
      (__attribute__((address_space(3))) unsigned int*)l, 16, 0, 0);
}

__device__ __forceinline__ void bar() { asm volatile("s_barrier" ::: "memory"); }

// LDS row = 64B = 4 chunks of 16B. Physical chunk = (logical + r + (r>>1)) & 3.
// (plain (c+r)&3 leaves rows==mod4 on one bank -> 4-way; the +r>>1 term spreads
//  even/odd row groups across all 4 chunk slots -> 2-way aliasing, free.)
__device__ __forceinline__ int swz(int c, int r) { return (c + r + (r >> 1)) & 3; }

// ---------------- fused pre-pass (unchanged) ----------------
// blocks [0,16384): y/adj f32->bf16 (float4->ushort4)
// blocks [16384,16640): W transpose+cvt (64x64 tiles)

__global__ __launch_bounds__(256) void k_prep(
    const float4* __restrict__ y4, const float4* __restrict__ a4,
    ushort4* __restrict__ yb, ushort4* __restrict__ ab,
    const float* __restrict__ W, unsigned short* __restrict__ Wt)
{
  __shared__ float t[64][65];
  const int bid = blockIdx.x;
  if (bid < 16384) {
    const int i = bid * 256 + threadIdx.x;
    const bool isY = i < 2097152;
    const float4 v = isY ? y4[i] : a4[i - 2097152];
    ushort4 p;
    p.x = f2bf(v.x); p.y = f2bf(v.y); p.z = f2bf(v.z); p.w = f2bf(v.w);
    if (isY) yb[i] = p; else ab[i - 2097152] = p;
  } else {
    const int id = bid - 16384;
    const int n0 = (id & 15) * 64, k0 = (id >> 4) * 64;
    const int tx = threadIdx.x & 63, ty = threadIdx.x >> 6;
#pragma unroll
    for (int r = ty; r < 64; r += 4)
      t[r][tx] = W[(size_t)(k0 + r) * 1024 + n0 + tx];
    __syncthreads();
#pragma unroll
    for (int r = ty; r < 64; r += 4)
      Wt[(size_t)(n0 + r) * 1024 + k0 + tx] = f2bf(t[tx][r]);
  }
}

// ---------------- GEMM pieces: 128x64 tile, BK=32 ----------------
// A-tile 128x32 bf16 = 8KB (512 granules), B-tile 64x32 = 4KB (256 granules).
// Per thread per K-tile: 2 A-loads + 1 B-load = 3 gload_lds -> vmcnt(3).

__device__ __forceinline__ void stage32(
    const unsigned short* __restrict__ A,  int sA,
    const unsigned short* __restrict__ Bt, int sB,
    int m0, int n0, int k0,
    unsigned short* la, unsigned short* lb,
    int wave, int lane)
{
  const int p = lane & 3;                      // physical chunk this lane writes
#pragma unroll
  for (int s = 0; s < 2; ++s) {
    const int gid = wave * 128 + s * 64 + lane;   // 0..511 granules of A
    const int r = gid >> 2;                       // row 0..127
    const int c = (p - r - (r >> 1)) & 3;         // inverse-swizzled source chunk
    async_cp16(A + (size_t)(m0 + r) * sA + k0 + c * 8,
               la + (wave * 128 + s * 64) * 8);
  }
  {
    const int gid = wave * 64 + lane;             // 0..255 granules of B
    const int r = gid >> 2;                       // row 0..63
    const int c = (p - r - (r >> 1)) & 3;
    async_cp16(Bt + (size_t)(n0 + r) * sB + k0 + c * 8,
               lb + (wave * 64) * 8);
  }
}

__device__ __forceinline__ void compute32(
    const unsigned short* la, const unsigned short* lb,
    f32x4 acc[4][2], int wm, int wn, int quad, int l16)
{
  bf16x8 af[4], bfr[2];
#pragma unroll
  for (int i = 0; i < 4; ++i) {
    const int r = wm + i * 16 + l16;
    af[i] = *(const bf16x8*)(la + r * 32 + swz(quad, r) * 8);
  }
#pragma unroll
  for (int j = 0; j < 2; ++j) {
    const int r = wn + j * 16 + l16;
    bfr[j] = *(const bf16x8*)(lb + r * 32 + swz(quad, r) * 8);
  }
#pragma unroll
  for (int i = 0; i < 4; ++i)
#pragma unroll
    for (int j = 0; j < 2; ++j)
      acc[i][j] = __builtin_amdgcn_mfma_f32_16x16x32_bf16(af[i], bfr[j], acc[i][j], 0, 0, 0);
}

// Double-buffered mainloop: issue(next) -> vmcnt(3) waits prev tile only ->
// barrier -> compute -> barrier. 32 K-tiles, 2 per iteration.
__device__ __forceinline__ void gemm_dbuf32(
    const unsigned short* __restrict__ A,  int sA,
    const unsigned short* __restrict__ Bt, int sB,
    int m0, int n0, f32x4 acc[4][2], unsigned short* lsm, int tid)
{
  const int lane = tid & 63, wave = tid >> 6;
  const int wm = (wave >> 1) * 64, wn = (wave & 1) * 32;
  const int quad = lane >> 4, l16 = lane & 15;
  unsigned short* la0 = lsm;            // 4096 ushorts = 8KB
  unsigned short* lb0 = lsm + 4096;     // 2048 ushorts = 4KB
  unsigned short* la1 = lsm + 6144;
  unsigned short* lb1 = lsm + 10240;    // total 12288 ushorts = 24KB

  stage32(A, sA, Bt, sB, m0, n0, 0, la0, lb0, wave, lane);
#pragma unroll 1
  for (int k0 = 0; k0 < 1024; k0 += 64) {
    stage32(A, sA, Bt, sB, m0, n0, k0 + 32, la1, lb1, wave, lane);
    asm volatile("s_waitcnt vmcnt(3)" ::: "memory");
    bar();
    compute32(la0, lb0, acc, wm, wn, quad, l16);
    bar();
    if (k0 + 64 < 1024) {
      stage32(A, sA, Bt, sB, m0, n0, k0 + 64, la0, lb0, wave, lane);
      asm volatile("s_waitcnt vmcnt(3)" ::: "memory");
    } else {
      asm volatile("s_waitcnt vmcnt(0)" ::: "memory");
    }
    bar();
    compute32(la1, lb1, acc, wm, wn, quad, l16);
    bar();
  }
}

__device__ __forceinline__ void zero_acc(f32x4 acc[4][2]) {
#pragma unroll
  for (int i = 0; i < 4; ++i)
#pragma unroll
    for (int j = 0; j < 2; ++j)
#pragma unroll
      for (int r = 0; r < 4; ++r) acc[i][j][r] = 0.0f;
}

// ---------------- GEMM1: Sup2[d][b*1024+n] = (y@W)^T ----------------

__global__ __launch_bounds__(256, 4) void k_gemm1(
    const unsigned short* __restrict__ Wt,    // [1024][1024]
    const unsigned short* __restrict__ Ybf,   // [8192][1024]
    unsigned short* __restrict__ Sup2)        // [1024][8192]
{
  __shared__ __align__(16) unsigned short lsm[12288];
  const int tid = threadIdx.x;
  const int n0 = blockIdx.x * 64, m0 = blockIdx.y * 128;

  f32x4 acc[4][2];
  zero_acc(acc);
  gemm_dbuf32(Wt, 1024, Ybf, 1024, m0, n0, acc, lsm, tid);

  const int lane = tid & 63, wave = tid >> 6;
  const int wm = (wave >> 1) * 64, wn = (wave & 1) * 32;
  const int quad = lane >> 4, l16 = lane & 15;
#pragma unroll
  for (int i = 0; i < 4; ++i) {
    const int mb = m0 + wm + i * 16 + quad * 4;
#pragma unroll
    for (int r = 0; r < 4; ++r) {
      unsigned short* row = Sup2 + ((size_t)(mb + r) << 13);
#pragma unroll
      for (int j = 0; j < 2; ++j)
        row[n0 + wn + j * 16 + l16] = f2bf(acc[i][j][r]);
    }
  }
}

// ------- GEMM2: out = relu(adj@support / rowsum + bias + x) -------

__global__ __launch_bounds__(256, 4) void k_gemm2(
    const unsigned short* __restrict__ AdjBf, // [8][1024][1024]
    const unsigned short* __restrict__ Sup2,  // [1024][8192]
    const float* __restrict__ x,
    const float* __restrict__ sumrow,         // [8][1024]
    const float* __restrict__ bias,           // [1024]
    float* __restrict__ out)
{
  __shared__ __align__(16) unsigned short lsm[12288];
  const int tid = threadIdx.x;
  const int n0 = blockIdx.x * 64, m0 = blockIdx.y * 128, b = blockIdx.z;

  f32x4 acc[4][2];
  zero_acc(acc);
  gemm_dbuf32(AdjBf + ((size_t)b << 20), 1024,
              Sup2 + ((size_t)b << 10), 8192,
              m0, n0, acc, lsm, tid);

  const float* xb = x   + ((size_t)b << 20);
  float*       ob = out + ((size_t)b << 20);
  const float* sr = sumrow + ((size_t)b << 10);
  const int lane = tid & 63, wave = tid >> 6;
  const int wm = (wave >> 1) * 64, wn = (wave & 1) * 32;
  const int quad = lane >> 4, l16 = lane & 15;

  float bv[2];
#pragma unroll
  for (int j = 0; j < 2; ++j) bv[j] = bias[n0 + wn + j * 16 + l16];

#pragma unroll
  for (int i = 0; i < 4; ++i) {
    const int mb = m0 + wm + i * 16 + quad * 4;
#pragma unroll
    for (int r = 0; r < 4; ++r) {
      const int m = mb + r;
      const float inv = 1.0f / sr[m];
#pragma unroll
      for (int j = 0; j < 2; ++j) {
        const int n = n0 + wn + j * 16 + l16;
        const size_t idx = (((size_t)m) << 10) + n;
        float v = acc[i][j][r] * inv + bv[j] + xb[idx];
        ob[idx] = fmaxf(v, 0.0f);
      }
    }
  }
}

// ---------------- launcher ----------------

extern "C" void kernel_launch(void* const* d_in, const int* in_sizes, int n_in,
                              void* d_out, int out_size, void* d_ws, size_t ws_size,
                              hipStream_t stream) {
  const float* x      = (const float*)d_in[0];
  const float* y      = (const float*)d_in[1];
  const float* adj    = (const float*)d_in[2];
  const float* sumrow = (const float*)d_in[3];
  const float* W      = (const float*)d_in[4];
  const float* bias   = (const float*)d_in[5];
  float* out = (float*)d_out;

  char* ws = (char*)d_ws;
  unsigned short* ybf   = (unsigned short*)(ws);                       // 16 MB
  unsigned short* adjbf = (unsigned short*)(ws + ((size_t)16 << 20));  // 16 MB
  unsigned short* wt    = (unsigned short*)(ws + ((size_t)32 << 20));  //  2 MB
  unsigned short* sup2  = (unsigned short*)(ws + ((size_t)34 << 20));  // 16 MB

  k_prep<<<dim3(16640), dim3(256), 0, stream>>>(
      (const float4*)y, (const float4*)adj, (ushort4*)ybf, (ushort4*)adjbf, W, wt);
  k_gemm1<<<dim3(128, 8), dim3(256), 0, stream>>>(wt, ybf, sup2);
  k_gemm2<<<dim3(16, 8, 8), dim3(256), 0, stream>>>(adjbf, sup2, x, sumrow, bias, out);
}

// Round 2
// 196.675 us; speedup vs baseline: 1.1063x; 1.1063x over previous
//
#include <hip/hip_runtime.h>
#include <hip/hip_bf16.h>
#include <stdint.h>

// B=8, N=1024, D=1024.  out = relu(adj @ (y@W) / adj_sumrow + b + x)
// R5: back to R3's proven 128x128xBK64 counted-vmcnt pipeline, but 512-thread
// blocks (8 waves, 4 loads/thread/stage). LDS stays 64KB -> 2 blocks/CU, so
// waves/CU doubles 8->16 (4/SIMD) with 2 independent barrier groups per CU.
// Per-phase per-SIMD MFMA work unchanged vs R3; latency hiding doubles.

typedef float  f32x4  __attribute__((ext_vector_type(4)));
typedef __bf16 bf16x8 __attribute__((ext_vector_type(8)));

__device__ __forceinline__ unsigned short f2bf(float f) {
  union { float f; unsigned int u; } c; c.f = f;
  unsigned int u = c.u;
  u += 0x7FFFu + ((u >> 16) & 1u);   // RNE; inputs finite
  return (unsigned short)(u >> 16);
}

__device__ __forceinline__ void async_cp16(const void* g, void* l) {
  __builtin_amdgcn_global_load_lds(
      (const __attribute__((address_space(1))) unsigned int*)g,
      (__attribute__((address_space(3))) unsigned int*)l, 16, 0, 0);
}

__device__ __forceinline__ void bar() { asm volatile("s_barrier" ::: "memory"); }

// ---------------- fused pre-pass (unchanged from R3) ----------------
// blocks [0,16384): y/adj f32->bf16 (float4->ushort4)
// blocks [16384,16640): W transpose+cvt (64x64 tiles)

__global__ __launch_bounds__(256) void k_prep(
    const float4* __restrict__ y4, const float4* __restrict__ a4,
    ushort4* __restrict__ yb, ushort4* __restrict__ ab,
    const float* __restrict__ W, unsigned short* __restrict__ Wt)
{
  __shared__ float t[64][65];
  const int bid = blockIdx.x;
  if (bid < 16384) {
    const int i = bid * 256 + threadIdx.x;
    const bool isY = i < 2097152;
    const float4 v = isY ? y4[i] : a4[i - 2097152];
    ushort4 p;
    p.x = f2bf(v.x); p.y = f2bf(v.y); p.z = f2bf(v.z); p.w = f2bf(v.w);
    if (isY) yb[i] = p; else ab[i - 2097152] = p;
  } else {
    const int id = bid - 16384;
    const int n0 = (id & 15) * 64, k0 = (id >> 4) * 64;
    const int tx = threadIdx.x & 63, ty = threadIdx.x >> 6;
#pragma unroll
    for (int r = ty; r < 64; r += 4)
      t[r][tx] = W[(size_t)(k0 + r) * 1024 + n0 + tx];
    __syncthreads();
#pragma unroll
    for (int r = ty; r < 64; r += 4)
      Wt[(size_t)(n0 + r) * 1024 + k0 + tx] = f2bf(t[tx][r]);
  }
}

// ---------------- GEMM pieces: 128x128 tile, BK=64, 8 waves ----------------
// LDS row = 128B = 8 chunks of 16B; physical chunk = (logical + row) & 7.
// Staging applies inverse permutation on the global column (free).
// 512 threads: A-tile 128x64 = 1024 granules (2/thread), B same -> 4 loads/thread.

__device__ __forceinline__ void stage512(
    const unsigned short* __restrict__ A,  int sA,
    const unsigned short* __restrict__ Bt, int sB,
    int m0, int n0, int k0,
    unsigned short* la, unsigned short* lb,
    int wave, int rg, int colo)
{
#pragma unroll
  for (int s = 0; s < 2; ++s) {
    const int t = wave * 2 + s;                  // wave-uniform granule-group id
    async_cp16(A  + (size_t)(m0 + t * 8 + rg) * sA + k0 + colo, la + t * 512);
    async_cp16(Bt + (size_t)(n0 + t * 8 + rg) * sB + k0 + colo, lb + t * 512);
  }
}

// Per-wave output 32x64: waves 4M x 2N. acc[2][4]. 16 MFMA per K-tile.
__device__ __forceinline__ void compute512(
    const unsigned short* la, const unsigned short* lb,
    f32x4 acc[2][4], int wm, int wn, int quad, int l16)
{
#pragma unroll
  for (int h = 0; h < 2; ++h) {
    bf16x8 af[2], bfr[4];
#pragma unroll
    for (int i = 0; i < 2; ++i) {
      const int r = wm + i * 16 + l16;
      af[i] = *(const bf16x8*)(la + r * 64 + ((h * 4 + quad + r) & 7) * 8);
    }
#pragma unroll
    for (int j = 0; j < 4; ++j) {
      const int r = wn + j * 16 + l16;
      bfr[j] = *(const bf16x8*)(lb + r * 64 + ((h * 4 + quad + r) & 7) * 8);
    }
#pragma unroll
    for (int i = 0; i < 2; ++i)
#pragma unroll
      for (int j = 0; j < 4; ++j)
        acc[i][j] = __builtin_amdgcn_mfma_f32_16x16x32_bf16(af[i], bfr[j], acc[i][j], 0, 0, 0);
  }
}

// Double-buffered mainloop: per stage each thread issues 4 global_load_lds.
// issue(next) -> vmcnt(4) waits prev stage only -> barrier -> compute -> barrier.
__device__ __forceinline__ void gemm_dbuf(
    const unsigned short* __restrict__ A,  int sA,
    const unsigned short* __restrict__ Bt, int sB,
    int m0, int n0, f32x4 acc[2][4], unsigned short* lsm, int tid)
{
  const int lane = tid & 63, wave = tid >> 6;
  const int wm = (wave >> 1) * 32, wn = (wave & 1) * 64;
  const int quad = lane >> 4, l16 = lane & 15;
  const int rg = lane >> 3;
  const int colo = (((lane & 7) - rg) & 7) * 8;    // inverse-swizzled k-offset
  unsigned short* la0 = lsm;
  unsigned short* lb0 = lsm + 8192;
  unsigned short* la1 = lsm + 16384;
  unsigned short* lb1 = lsm + 24576;

  stage512(A, sA, Bt, sB, m0, n0, 0, la0, lb0, wave, rg, colo);
#pragma unroll 1
  for (int k0 = 0; k0 < 1024; k0 += 128) {
    // stage A: compute buf0 @ k0, prefetch k0+64 into buf1
    stage512(A, sA, Bt, sB, m0, n0, k0 + 64, la1, lb1, wave, rg, colo);
    asm volatile("s_waitcnt vmcnt(4)" ::: "memory");
    bar();
    compute512(la0, lb0, acc, wm, wn, quad, l16);
    bar();
    // stage B: compute buf1 @ k0+64, prefetch k0+128 into buf0
    if (k0 + 128 < 1024) {
      stage512(A, sA, Bt, sB, m0, n0, k0 + 128, la0, lb0, wave, rg, colo);
      asm volatile("s_waitcnt vmcnt(4)" ::: "memory");
    } else {
      asm volatile("s_waitcnt vmcnt(0)" ::: "memory");
    }
    bar();
    compute512(la1, lb1, acc, wm, wn, quad, l16);
    bar();
  }
}

__device__ __forceinline__ void zero_acc(f32x4 acc[2][4]) {
#pragma unroll
  for (int i = 0; i < 2; ++i)
#pragma unroll
    for (int j = 0; j < 4; ++j)
#pragma unroll
      for (int r = 0; r < 4; ++r) acc[i][j][r] = 0.0f;
}

// ---------------- GEMM1: Sup2[d][b*1024+n] = (y@W)^T ----------------

__global__ __launch_bounds__(512, 4) void k_gemm1(
    const unsigned short* __restrict__ Wt,    // [1024][1024]
    const unsigned short* __restrict__ Ybf,   // [8192][1024]
    unsigned short* __restrict__ Sup2)        // [1024][8192]
{
  __shared__ __align__(16) unsigned short lsm[4 * 8192];
  const int tid = threadIdx.x;
  const int n0 = blockIdx.x * 128, m0 = blockIdx.y * 128;

  f32x4 acc[2][4];
  zero_acc(acc);
  gemm_dbuf(Wt, 1024, Ybf, 1024, m0, n0, acc, lsm, tid);

  const int lane = tid & 63, wave = tid >> 6;
  const int wm = (wave >> 1) * 32, wn = (wave & 1) * 64;
  const int quad = lane >> 4, l16 = lane & 15;
#pragma unroll
  for (int i = 0; i < 2; ++i) {
    const int mb = m0 + wm + i * 16 + quad * 4;
#pragma unroll
    for (int r = 0; r < 4; ++r) {
      unsigned short* row = Sup2 + ((size_t)(mb + r) << 13);
#pragma unroll
      for (int j = 0; j < 4; ++j)
        row[n0 + wn + j * 16 + l16] = f2bf(acc[i][j][r]);
    }
  }
}

// ------- GEMM2: out = relu(adj@support / rowsum + bias + x) -------

__global__ __launch_bounds__(512, 4) void k_gemm2(
    const unsigned short* __restrict__ AdjBf, // [8][1024][1024]
    const unsigned short* __restrict__ Sup2,  // [1024][8192]
    const float* __restrict__ x,
    const float* __restrict__ sumrow,         // [8][1024]
    const float* __restrict__ bias,           // [1024]
    float* __restrict__ out)
{
  __shared__ __align__(16) unsigned short lsm[4 * 8192];
  const int tid = threadIdx.x;
  const int n0 = blockIdx.x * 128, m0 = blockIdx.y * 128, b = blockIdx.z;

  f32x4 acc[2][4];
  zero_acc(acc);
  gemm_dbuf(AdjBf + ((size_t)b << 20), 1024,
            Sup2 + ((size_t)b << 10), 8192,
            m0, n0, acc, lsm, tid);

  const float* xb = x   + ((size_t)b << 20);
  float*       ob = out + ((size_t)b << 20);
  const float* sr = sumrow + ((size_t)b << 10);
  const int lane = tid & 63, wave = tid >> 6;
  const int wm = (wave >> 1) * 32, wn = (wave & 1) * 64;
  const int quad = lane >> 4, l16 = lane & 15;

  float bv[4];
#pragma unroll
  for (int j = 0; j < 4; ++j) bv[j] = bias[n0 + wn + j * 16 + l16];

#pragma unroll
  for (int i = 0; i < 2; ++i) {
    const int mb = m0 + wm + i * 16 + quad * 4;
#pragma unroll
    for (int r = 0; r < 4; ++r) {
      const int m = mb + r;
      const float inv = 1.0f / sr[m];
#pragma unroll
      for (int j = 0; j < 4; ++j) {
        const int n = n0 + wn + j * 16 + l16;
        const size_t idx = (((size_t)m) << 10) + n;
        float v = acc[i][j][r] * inv + bv[j] + xb[idx];
        ob[idx] = fmaxf(v, 0.0f);
      }
    }
  }
}

// ---------------- launcher ----------------

extern "C" void kernel_launch(void* const* d_in, const int* in_sizes, int n_in,
                              void* d_out, int out_size, void* d_ws, size_t ws_size,
                              hipStream_t stream) {
  const float* x      = (const float*)d_in[0];
  const float* y      = (const float*)d_in[1];
  const float* adj    = (const float*)d_in[2];
  const float* sumrow = (const float*)d_in[3];
  const float* W      = (const float*)d_in[4];
  const float* bias   = (const float*)d_in[5];
  float* out = (float*)d_out;

  char* ws = (char*)d_ws;
  unsigned short* ybf   = (unsigned short*)(ws);                       // 16 MB
  unsigned short* adjbf = (unsigned short*)(ws + ((size_t)16 << 20));  // 16 MB
  unsigned short* wt    = (unsigned short*)(ws + ((size_t)32 << 20));  //  2 MB
  unsigned short* sup2  = (unsigned short*)(ws + ((size_t)34 << 20));  // 16 MB

  k_prep<<<dim3(16640), dim3(256), 0, stream>>>(
      (const float4*)y, (const float4*)adj, (ushort4*)ybf, (ushort4*)adjbf, W, wt);
  k_gemm1<<<dim3(64, 8), dim3(512), 0, stream>>>(wt, ybf, sup2);
  k_gemm2<<<dim3(8, 8, 8), dim3(512), 0, stream>>>(adjbf, sup2, x, sumrow, bias, out);
}